// Round 6
// baseline (1446.507 us; speedup 1.0000x reference)
//
#include <hip/hip_runtime.h>
#include <hip/hip_fp16.h>
#include <math.h>

#define D 64
#define NPB 64           // nodes per bucket
#define NPB_SHIFT 6
#define LCAP 2560        // LDS csr capacity per bucket (mean ~1024, sigma ~32)
#define NPART 64         // edge partitions (one workgroup each)
#define ASTRIDE 68       // accS row stride (64 + 4 pad -> conflict-free atomics)

// ---------------- generic exclusive scan chain ----------------

__global__ void scan1_kernel(const int* __restrict__ in, int* __restrict__ out,
                             int* __restrict__ bsum, int n) {
    __shared__ int s[1024];
    int t = threadIdx.x;
    int i = blockIdx.x * 1024 + t;
    int v = (i < n) ? in[i] : 0;
    s[t] = v;
    __syncthreads();
    for (int off = 1; off < 1024; off <<= 1) {
        int add = (t >= off) ? s[t - off] : 0;
        __syncthreads();
        s[t] += add;
        __syncthreads();
    }
    if (i < n) out[i] = s[t] - v;
    if (t == 1023) bsum[blockIdx.x] = s[1023];
}

__global__ void scan2_kernel(int* __restrict__ bsum, int nb) {
    __shared__ int s[128];
    int t = threadIdx.x;
    int v = (t < nb) ? bsum[t] : 0;
    s[t] = v;
    __syncthreads();
    for (int off = 1; off < 128; off <<= 1) {
        int add = (t >= off) ? s[t - off] : 0;
        __syncthreads();
        s[t] += add;
        __syncthreads();
    }
    if (t < nb) bsum[t] = s[t] - v;
}

__global__ void scan3_kernel(int* __restrict__ out, const int* __restrict__ bsum, int n) {
    int i = blockIdx.x * 1024 + threadIdx.x;
    if (i < n) out[i] += bsum[blockIdx.x];
}

// ---------------- two-level counting sort (no global atomics) ----------------

__global__ __launch_bounds__(256) void part_hist_kernel(
    const int* __restrict__ dst, int* __restrict__ harr,
    int e, int nb, int chunk)
{
    extern __shared__ int sh[];
    const int p = blockIdx.x;
    for (int i = threadIdx.x; i < nb; i += 256) sh[i] = 0;
    __syncthreads();
    const int s = p * chunk, ee = min(e, s + chunk);
    for (int i = s + threadIdx.x; i < ee; i += 256)
        atomicAdd(&sh[dst[i] >> NPB_SHIFT], 1);
    __syncthreads();
    for (int b = threadIdx.x; b < nb; b += 256) harr[b * NPART + p] = sh[b];
}

__global__ __launch_bounds__(256) void part_scatter_kernel(
    const int* __restrict__ src, const int* __restrict__ dst,
    const int* __restrict__ soff, int2* __restrict__ pairs,
    int e, int nb, int chunk)
{
    extern __shared__ int cur[];
    const int p = blockIdx.x;
    for (int b = threadIdx.x; b < nb; b += 256) cur[b] = soff[b * NPART + p];
    __syncthreads();
    const int s = p * chunk, ee = min(e, s + chunk);
    for (int i = s + threadIdx.x; i < ee; i += 256) {
        int d = dst[i];
        int pos = atomicAdd(&cur[d >> NPB_SHIFT], 1);
        pairs[pos] = make_int2(src[i], d);
    }
}

// per-bucket: stage pairs in LDS, per-node deg, place csr + local-dst (eloc)
__global__ __launch_bounds__(256) void bucket_build_kernel(
    const int* __restrict__ soff, const int2* __restrict__ pairs,
    int* __restrict__ csr, unsigned char* __restrict__ eloc,
    int* __restrict__ deg, int n, int e_total, int nb)
{
    __shared__ int2 sp[LCAP];
    __shared__ int lcsr[LCAP];
    __shared__ unsigned char lloc[LCAP];
    __shared__ int dcount[NPB];
    __shared__ int dexcl[NPB];
    __shared__ int cur2[NPB];
    const int b    = blockIdx.x;
    const int base = soff[b * NPART];
    const int end  = (b + 1 < nb) ? soff[(b + 1) * NPART] : e_total;
    const int cnt  = end - base;
    const int nb0  = b << NPB_SHIFT;
    const int nnode = min(NPB, n - nb0);
    const int tid  = threadIdx.x;

    if (tid < NPB) { dcount[tid] = 0; cur2[tid] = 0; }
    __syncthreads();

    if (cnt <= LCAP) {
        for (int i = tid; i < cnt; i += 256) sp[i] = pairs[base + i];
        __syncthreads();
        for (int i = tid; i < cnt; i += 256) atomicAdd(&dcount[sp[i].y & (NPB - 1)], 1);
        __syncthreads();
        if (tid == 0) {
            int run = 0;
            for (int t = 0; t < nnode; ++t) { dexcl[t] = run; run += dcount[t]; }
        }
        __syncthreads();
        if (tid < nnode) deg[nb0 + tid] = dcount[tid];
        for (int i = tid; i < cnt; i += 256) {
            int2 pr = sp[i];
            int ln = pr.y & (NPB - 1);
            int pos = dexcl[ln] + atomicAdd(&cur2[ln], 1);
            lcsr[pos] = pr.x;
            lloc[pos] = (unsigned char)ln;
        }
        __syncthreads();
        for (int i = tid; i < cnt; i += 256) {
            csr[base + i]  = lcsr[i];
            eloc[base + i] = lloc[i];
        }
    } else {  // statistically unreachable fallback
        for (int i = tid; i < cnt; i += 256) atomicAdd(&dcount[pairs[base + i].y & (NPB - 1)], 1);
        __syncthreads();
        if (tid == 0) {
            int run = 0;
            for (int t = 0; t < nnode; ++t) { dexcl[t] = run; run += dcount[t]; }
        }
        __syncthreads();
        if (tid < nnode) deg[nb0 + tid] = dcount[tid];
        for (int i = tid; i < cnt; i += 256) {
            int2 pr = pairs[base + i];
            int ln = pr.y & (NPB - 1);
            int pos = dexcl[ln] + atomicAdd(&cur2[ln], 1);
            csr[base + pos]  = pr.x;
            eloc[base + pos] = (unsigned char)ln;
        }
    }
}

// ---------------- fp32 -> fp16 conversion ----------------

__global__ __launch_bounds__(256) void f2h_kernel(const float* __restrict__ in,
                                                  __half* __restrict__ out, int n4) {
    int i = blockIdx.x * blockDim.x + threadIdx.x;
    if (i < n4) {
        float4 v = *(const float4*)(in + (size_t)i * 4);
        union { __half2 h[2]; float2 f; } u;
        u.h[0] = __floats2half2_rn(v.x, v.y);
        u.h[1] = __floats2half2_rn(v.z, v.w);
        *(float2*)(out + (size_t)i * 4) = u.f;
    }
}

// ---------------- SAGE layer: edge-parallel, LDS accumulate ----------------
// One block per 64-node bucket. Edge phase: thread=(slot,chunk); slot owns a
// contiguous ~cnt/32 run of edges (slots >=32 edges apart -> distinct dst);
// per edge: 16B row-chunk gather + 8 LDS atomicAdd into accS (stride 68 ->
// conflict-free). Output phase: wave per node slice, broadcast-LDS GEMM,
// W read through L1 (16KB, fits).

__device__ __forceinline__ void unpack8(float4 f, float* x) {
    __half2* h = reinterpret_cast<__half2*>(&f);
    #pragma unroll
    for (int i = 0; i < 4; ++i) {
        float2 t = __half22float2(h[i]);
        x[2 * i] = t.x; x[2 * i + 1] = t.y;
    }
}

template<int RELU>
__global__ __launch_bounds__(256) void sage_bucket_kernel(
    const __half* __restrict__ in, __half* __restrict__ out,
    const float* __restrict__ W, const float* __restrict__ bias,
    const int* __restrict__ soff, const int* __restrict__ deg,
    const int* __restrict__ csr, const unsigned char* __restrict__ eloc,
    int n, int e_total, int nb)
{
    __shared__ float accS[NPB * ASTRIDE];
    const int b    = blockIdx.x;
    const int base = soff[b * NPART];
    const int end  = (b + 1 < nb) ? soff[(b + 1) * NPART] : e_total;
    const int cnt  = end - base;
    const int nb0  = b << NPB_SHIFT;
    const int nnode = min(NPB, n - nb0);
    const int tid  = threadIdx.x;

    for (int i = tid; i < NPB * ASTRIDE; i += 256) accS[i] = 0.0f;
    __syncthreads();

    const int c    = tid & 7;     // dim chunk (8 halves)
    const int slot = tid >> 3;    // 0..31
    const int run  = (cnt + 31) >> 5;
    const int i0   = base + slot * run;
    const int i1   = min(end, i0 + run);

    int i = i0;
    for (; i + 2 <= i1; i += 2) {
        int s0 = csr[i],  s1 = csr[i + 1];
        int l0 = eloc[i], l1 = eloc[i + 1];
        float4 f0 = *(const float4*)(in + (size_t)s0 * D + c * 8);
        float4 f1 = *(const float4*)(in + (size_t)s1 * D + c * 8);
        float x[8], y[8];
        unpack8(f0, x); unpack8(f1, y);
        float* a0 = &accS[l0 * ASTRIDE + c * 8];
        float* a1 = &accS[l1 * ASTRIDE + c * 8];
        #pragma unroll
        for (int j = 0; j < 8; ++j) atomicAdd(&a0[j], x[j]);
        #pragma unroll
        for (int j = 0; j < 8; ++j) atomicAdd(&a1[j], y[j]);
    }
    for (; i < i1; ++i) {
        int s0 = csr[i];
        int l0 = eloc[i];
        float4 f0 = *(const float4*)(in + (size_t)s0 * D + c * 8);
        float x[8]; unpack8(f0, x);
        float* a0 = &accS[l0 * ASTRIDE + c * 8];
        #pragma unroll
        for (int j = 0; j < 8; ++j) atomicAdd(&a0[j], x[j]);
    }
    __syncthreads();

    // ---- output phase: wave w handles nodes w, w+4, ... ----
    const int lane = tid & 63;
    const int w    = tid >> 6;
    for (int ln = w; ln < nnode; ln += 4) {
        const int v = nb0 + ln;
        float self = __half2float(in[(size_t)v * D + lane]);
        float inv  = 1.0f / (float)(deg[v] + 1);
        float a = (accS[ln * ASTRIDE + lane] + self) * inv;
        accS[ln * ASTRIDE + lane] = a;          // intra-wave visible
        float o = bias[lane];
        #pragma unroll 16
        for (int k = 0; k < D; ++k) {
            o = fmaf(accS[ln * ASTRIDE + k], W[k * D + lane], o);
        }
        if (RELU) o = fmaxf(o, 0.0f);
        out[(size_t)v * D + lane] = __float2half(o);
    }
}

// ---------------- Scoring ----------------

__global__ __launch_bounds__(256) void score_kernel(
    const __half* __restrict__ emb,
    const int* __restrict__ a_idx, const int* __restrict__ b_idx,
    int npairs, float sign, double* __restrict__ accum)
{
    const int ll  = threadIdx.x & 7;
    const int gib = threadIdx.x >> 3;
    const int gpb = blockDim.x >> 3;
    int g = blockIdx.x * gpb + gib;
    const int stride = gridDim.x * gpb;

    float local = 0.0f;
    int p = g;
    for (; p + stride < npairs; p += 2 * stride) {
        int p2 = p + stride;
        int ai = a_idx[p],  bi = b_idx[p];
        int ci = a_idx[p2], di = b_idx[p2];
        float4 fa = *(const float4*)(emb + (size_t)ai * D + ll * 8);
        float4 fb = *(const float4*)(emb + (size_t)bi * D + ll * 8);
        float4 fc = *(const float4*)(emb + (size_t)ci * D + ll * 8);
        float4 fd = *(const float4*)(emb + (size_t)di * D + ll * 8);
        float A[8], B[8], C[8], E[8];
        unpack8(fa, A); unpack8(fb, B); unpack8(fc, C); unpack8(fd, E);
        float d0 = 0.f, d1 = 0.f;
        #pragma unroll
        for (int j = 0; j < 8; ++j) { d0 = fmaf(A[j], B[j], d0); d1 = fmaf(C[j], E[j], d1); }
        d0 += __shfl_xor(d0, 1); d1 += __shfl_xor(d1, 1);
        d0 += __shfl_xor(d0, 2); d1 += __shfl_xor(d1, 2);
        d0 += __shfl_xor(d0, 4); d1 += __shfl_xor(d1, 4);
        if (ll == 0) {
            float x0 = sign * d0, x1 = sign * d1;
            local += fmaxf(x0, 0.0f) + log1pf(expf(-fabsf(x0)));
            local += fmaxf(x1, 0.0f) + log1pf(expf(-fabsf(x1)));
        }
    }
    for (; p < npairs; p += stride) {
        int ai = a_idx[p], bi = b_idx[p];
        float4 fa = *(const float4*)(emb + (size_t)ai * D + ll * 8);
        float4 fb = *(const float4*)(emb + (size_t)bi * D + ll * 8);
        float A[8], B[8];
        unpack8(fa, A); unpack8(fb, B);
        float d = 0.f;
        #pragma unroll
        for (int j = 0; j < 8; ++j) d = fmaf(A[j], B[j], d);
        d += __shfl_xor(d, 1);
        d += __shfl_xor(d, 2);
        d += __shfl_xor(d, 4);
        if (ll == 0) {
            float x = sign * d;
            local += fmaxf(x, 0.0f) + log1pf(expf(-fabsf(x)));
        }
    }

    __shared__ float red[256];
    red[threadIdx.x] = local;
    __syncthreads();
    for (int s = blockDim.x / 2; s > 0; s >>= 1) {
        if ((int)threadIdx.x < s) red[threadIdx.x] += red[threadIdx.x + s];
        __syncthreads();
    }
    if (threadIdx.x == 0) atomicAdd(accum, (double)red[0]);
}

__global__ void finalize_kernel(const double* __restrict__ acc, float* __restrict__ out, int ep) {
    if (threadIdx.x == 0 && blockIdx.x == 0)
        out[0] = (float)(acc[0] / (double)ep);
}

// ---------------- launch ----------------

extern "C" void kernel_launch(void* const* d_in, const int* in_sizes, int n_in,
                              void* d_out, int out_size, void* d_ws, size_t ws_size,
                              hipStream_t stream) {
    const float* features = (const float*)d_in[0];
    const float* W1 = (const float*)d_in[1];
    const float* b1 = (const float*)d_in[2];
    const float* W2 = (const float*)d_in[3];
    const float* b2 = (const float*)d_in[4];
    const int* src     = (const int*)d_in[5];
    const int* dst     = (const int*)d_in[6];
    const int* pos_src = (const int*)d_in[7];
    const int* pos_dst = (const int*)d_in[8];
    const int* neg_src = (const int*)d_in[9];
    const int* neg_dst = (const int*)d_in[10];

    const int N    = in_sizes[0] / D;
    const int E    = in_sizes[5];
    const int EP   = in_sizes[7];
    const int ENEG = in_sizes[9];
    const int NB   = (N + NPB - 1) >> NPB_SHIFT;   // 1563 for N=100000

    char* ws = (char*)d_ws;
    size_t off = 0;
    auto alloc = [&](size_t bytes) -> void* {
        void* p = ws + off;
        off += (bytes + 255) & ~(size_t)255;
        return p;
    };
    int*    deg   = (int*)alloc((size_t)N * 4);
    int*    harr  = (int*)alloc((size_t)NB * NPART * 4);
    int*    soff  = (int*)alloc((size_t)NB * NPART * 4);
    int*    bsum  = (int*)alloc(1024 * 4);
    int*    csr   = (int*)alloc((size_t)E * 4);
    unsigned char* eloc = (unsigned char*)alloc((size_t)E);
    // pairs (E*8 B) and hH (N*D*2 B) never live simultaneously
    size_t blk_sz = (size_t)E * 8;
    size_t hh_sz  = (size_t)N * D * 2;
    void*  blk    = alloc(blk_sz > hh_sz ? blk_sz : hh_sz);
    int2*   pairs = (int2*)blk;
    __half* hH    = (__half*)blk;
    __half* featH = (__half*)alloc((size_t)N * D * 2);
    __half* embH  = (__half*)alloc((size_t)N * D * 2);
    double* acc   = (double*)alloc(8);

    hipMemsetAsync(acc, 0, 8, stream);

    const int chunk = (E + NPART - 1) / NPART;
    const size_t ldsNB = (size_t)NB * 4;

    part_hist_kernel<<<NPART, 256, ldsNB, stream>>>(dst, harr, E, NB, chunk);
    const int scn = NB * NPART;                   // 100,032
    const int nbs = (scn + 1023) / 1024;          // 98 <= 128
    scan1_kernel<<<nbs, 1024, 0, stream>>>(harr, soff, bsum, scn);
    scan2_kernel<<<1, 128, 0, stream>>>(bsum, nbs);
    scan3_kernel<<<nbs, 1024, 0, stream>>>(soff, bsum, scn);
    part_scatter_kernel<<<NPART, 256, ldsNB, stream>>>(src, dst, soff, pairs, E, NB, chunk);
    bucket_build_kernel<<<NB, 256, 0, stream>>>(soff, pairs, csr, eloc, deg, N, E, NB);

    const int n4 = (N * D) / 4;
    f2h_kernel<<<(n4 + 255) / 256, 256, 0, stream>>>(features, featH, n4);

    sage_bucket_kernel<1><<<NB, 256, 0, stream>>>(featH, hH, W1, b1, soff, deg, csr, eloc, N, E, NB);
    sage_bucket_kernel<0><<<NB, 256, 0, stream>>>(hH, embH, W2, b2, soff, deg, csr, eloc, N, E, NB);

    int pb = (EP + 31) / 32;  if (pb > 2048) pb = 2048;
    score_kernel<<<pb, 256, 0, stream>>>(embH, pos_src, pos_dst, EP, -1.0f, acc);
    int ngb = (ENEG + 31) / 32; if (ngb > 4096) ngb = 4096;
    score_kernel<<<ngb, 256, 0, stream>>>(embH, neg_src, neg_dst, ENEG, 1.0f, acc);

    finalize_kernel<<<1, 64, 0, stream>>>(acc, (float*)d_out, EP);
}

// Round 7
// 981.276 us; speedup vs baseline: 1.4741x; 1.4741x over previous
//
#include <hip/hip_runtime.h>
#include <hip/hip_fp16.h>
#include <math.h>

#define D 64
#define NPB 64           // nodes per bucket
#define NPB_SHIFT 6
#define LCAP 2560        // LDS capacity per bucket (mean ~1024)
#define NPART 64         // edge partitions
#define RUN 32           // edges per 8-lane group in agg_kernel

// ---------------- generic exclusive scan chain ----------------

__global__ void scan1_kernel(const int* __restrict__ in, int* __restrict__ out,
                             int* __restrict__ bsum, int n) {
    __shared__ int s[1024];
    int t = threadIdx.x;
    int i = blockIdx.x * 1024 + t;
    int v = (i < n) ? in[i] : 0;
    s[t] = v;
    __syncthreads();
    for (int off = 1; off < 1024; off <<= 1) {
        int add = (t >= off) ? s[t - off] : 0;
        __syncthreads();
        s[t] += add;
        __syncthreads();
    }
    if (i < n) out[i] = s[t] - v;
    if (t == 1023) bsum[blockIdx.x] = s[1023];
}

__global__ void scan2_kernel(int* __restrict__ bsum, int nb) {
    __shared__ int s[128];
    int t = threadIdx.x;
    int v = (t < nb) ? bsum[t] : 0;
    s[t] = v;
    __syncthreads();
    for (int off = 1; off < 128; off <<= 1) {
        int add = (t >= off) ? s[t - off] : 0;
        __syncthreads();
        s[t] += add;
        __syncthreads();
    }
    if (t < nb) bsum[t] = s[t] - v;
}

__global__ void scan3_kernel(int* __restrict__ out, const int* __restrict__ bsum, int n) {
    int i = blockIdx.x * 1024 + threadIdx.x;
    if (i < n) out[i] += bsum[blockIdx.x];
}

// ---------------- two-level counting sort (no global atomics) ----------------

__global__ __launch_bounds__(256) void part_hist_kernel(
    const int* __restrict__ dst, int* __restrict__ harr,
    int e, int nb, int chunk)
{
    extern __shared__ int sh[];
    const int p = blockIdx.x;
    for (int i = threadIdx.x; i < nb; i += 256) sh[i] = 0;
    __syncthreads();
    const int s = p * chunk, ee = min(e, s + chunk);
    for (int i = s + threadIdx.x; i < ee; i += 256)
        atomicAdd(&sh[dst[i] >> NPB_SHIFT], 1);
    __syncthreads();
    for (int b = threadIdx.x; b < nb; b += 256) harr[b * NPART + p] = sh[b];
}

__global__ __launch_bounds__(256) void part_scatter_kernel(
    const int* __restrict__ src, const int* __restrict__ dst,
    const int* __restrict__ soff, int2* __restrict__ pairs,
    int e, int nb, int chunk)
{
    extern __shared__ int cur[];
    const int p = blockIdx.x;
    for (int b = threadIdx.x; b < nb; b += 256) cur[b] = soff[b * NPART + p];
    __syncthreads();
    const int s = p * chunk, ee = min(e, s + chunk);
    for (int i = s + threadIdx.x; i < ee; i += 256) {
        int d = dst[i];
        int pos = atomicAdd(&cur[d >> NPB_SHIFT], 1);
        pairs[pos] = make_int2(src[i], d);
    }
}

// per-bucket: sort pairs by dst IN PLACE (node-sorted within bucket) + emit deg
__global__ __launch_bounds__(256) void bucket_build_kernel(
    const int* __restrict__ soff, int2* __restrict__ pairs,
    int* __restrict__ deg, int n, int e_total, int nb)
{
    __shared__ int2 lsp[LCAP];
    __shared__ int dcount[NPB];
    __shared__ int dexcl[NPB];
    __shared__ int cur2[NPB];
    const int b    = blockIdx.x;
    const int base = soff[b * NPART];
    const int end  = (b + 1 < nb) ? soff[(b + 1) * NPART] : e_total;
    const int cnt  = end - base;
    const int nb0  = b << NPB_SHIFT;
    const int nnode = min(NPB, n - nb0);
    const int tid  = threadIdx.x;

    if (tid < NPB) { dcount[tid] = 0; cur2[tid] = 0; }
    __syncthreads();

    // count
    for (int i = tid; i < cnt; i += 256)
        atomicAdd(&dcount[pairs[base + i].y & (NPB - 1)], 1);
    __syncthreads();
    if (tid == 0) {
        int run = 0;
        for (int t = 0; t < nnode; ++t) { dexcl[t] = run; run += dcount[t]; }
    }
    __syncthreads();
    if (tid < nnode) deg[nb0 + tid] = dcount[tid];

    if (cnt <= LCAP) {
        // place sorted into LDS, then coalesced write-back (in-place safe)
        for (int i = tid; i < cnt; i += 256) {
            int2 pr = pairs[base + i];
            int ln = pr.y & (NPB - 1);
            int pos = dexcl[ln] + atomicAdd(&cur2[ln], 1);
            lsp[pos] = pr;
        }
        __syncthreads();
        for (int i = tid; i < cnt; i += 256) pairs[base + i] = lsp[i];
    }
    // else: leave unsorted (agg_kernel stays correct via atomics, just more flushes)
}

// ---------------- fp32 -> fp16 conversion ----------------

__global__ __launch_bounds__(256) void f2h_kernel(const float* __restrict__ in,
                                                  __half* __restrict__ out, int n4) {
    int i = blockIdx.x * blockDim.x + threadIdx.x;
    if (i < n4) {
        float4 v = *(const float4*)(in + (size_t)i * 4);
        union { __half2 h[2]; float2 f; } u;
        u.h[0] = __floats2half2_rn(v.x, v.y);
        u.h[1] = __floats2half2_rn(v.z, v.w);
        *(float2*)(out + (size_t)i * 4) = u.f;
    }
}

// ---------------- aggregation pass 1: score-shaped gather + register accumulate ----------------
// 8 lanes per edge-row; each group owns RUN contiguous dst-sorted edges.
// Register acc (lane ll owns dims ll*8..ll*8+7); flush on dst-change via
// global fp32 atomicAdd into pre-zeroed agg. Prefetch-1 pipeline.

__device__ __forceinline__ void unpack8(float4 f, float* x) {
    __half2* h = reinterpret_cast<__half2*>(&f);
    #pragma unroll
    for (int i = 0; i < 4; ++i) {
        float2 t = __half22float2(h[i]);
        x[2 * i] = t.x; x[2 * i + 1] = t.y;
    }
}

__global__ __launch_bounds__(256) void agg_kernel(
    const __half* __restrict__ in, const int2* __restrict__ sp,
    float* __restrict__ agg, int e)
{
    const int ll = threadIdx.x & 7;
    const int g  = (blockIdx.x * 256 + threadIdx.x) >> 3;
    const int i0 = g * RUN;
    if (i0 >= e) return;
    const int i1 = min(e, i0 + RUN);

    float acc[8];
    #pragma unroll
    for (int j = 0; j < 8; ++j) acc[j] = 0.0f;

    int2  pr = sp[i0];
    float4 f = *(const float4*)(in + (size_t)pr.x * D + ll * 8);
    int  cur = pr.y;

    for (int i = i0; i < i1; ++i) {
        int2 prn; float4 fn;
        if (i + 1 < i1) {                      // issue next row before consuming current
            prn = sp[i + 1];
            fn  = *(const float4*)(in + (size_t)prn.x * D + ll * 8);
        }
        if (pr.y != cur) {                     // group-uniform flush
            #pragma unroll
            for (int j = 0; j < 8; ++j) {
                atomicAdd(&agg[(size_t)cur * D + ll * 8 + j], acc[j]);
                acc[j] = 0.0f;
            }
            cur = pr.y;
        }
        float x[8]; unpack8(f, x);
        #pragma unroll
        for (int j = 0; j < 8; ++j) acc[j] += x[j];
        pr = prn; f = fn;
    }
    #pragma unroll
    for (int j = 0; j < 8; ++j)
        atomicAdd(&agg[(size_t)cur * D + ll * 8 + j], acc[j]);
}

// ---------------- aggregation pass 2: normalize + GEMM (+ReLU), streaming ----------------

template<int RELU>
__global__ __launch_bounds__(512) void post_kernel(
    const __half* __restrict__ in, const float* __restrict__ agg,
    __half* __restrict__ out, const float* __restrict__ W,
    const float* __restrict__ bias, const int* __restrict__ deg, int n)
{
    __shared__ float Wl[D * D];
    __shared__ float bl[D];
    for (int i = threadIdx.x; i < D * D; i += blockDim.x) Wl[i] = W[i];
    if (threadIdx.x < D) bl[threadIdx.x] = bias[threadIdx.x];
    __syncthreads();

    const int lane = threadIdx.x & 63;
    const int wid  = threadIdx.x >> 6;
    const int v    = blockIdx.x * (blockDim.x >> 6) + wid;
    if (v >= n) return;

    float self = __half2float(in[(size_t)v * D + lane]);
    float a = (agg[(size_t)v * D + lane] + self) / ((float)deg[v] + 1.0f);

    float o = bl[lane];
    #pragma unroll
    for (int k = 0; k < D; ++k)
        o = fmaf(__shfl(a, k), Wl[k * D + lane], o);
    if (RELU) o = fmaxf(o, 0.0f);
    out[(size_t)v * D + lane] = __float2half(o);
}

// ---------------- Scoring ----------------

__global__ __launch_bounds__(256) void score_kernel(
    const __half* __restrict__ emb,
    const int* __restrict__ a_idx, const int* __restrict__ b_idx,
    int npairs, float sign, double* __restrict__ accum)
{
    const int ll  = threadIdx.x & 7;
    const int gib = threadIdx.x >> 3;
    const int gpb = blockDim.x >> 3;
    int g = blockIdx.x * gpb + gib;
    const int stride = gridDim.x * gpb;

    float local = 0.0f;
    int p = g;
    for (; p + stride < npairs; p += 2 * stride) {
        int p2 = p + stride;
        int ai = a_idx[p],  bi = b_idx[p];
        int ci = a_idx[p2], di = b_idx[p2];
        float4 fa = *(const float4*)(emb + (size_t)ai * D + ll * 8);
        float4 fb = *(const float4*)(emb + (size_t)bi * D + ll * 8);
        float4 fc = *(const float4*)(emb + (size_t)ci * D + ll * 8);
        float4 fd = *(const float4*)(emb + (size_t)di * D + ll * 8);
        float A[8], B[8], C[8], E[8];
        unpack8(fa, A); unpack8(fb, B); unpack8(fc, C); unpack8(fd, E);
        float d0 = 0.f, d1 = 0.f;
        #pragma unroll
        for (int j = 0; j < 8; ++j) { d0 = fmaf(A[j], B[j], d0); d1 = fmaf(C[j], E[j], d1); }
        d0 += __shfl_xor(d0, 1); d1 += __shfl_xor(d1, 1);
        d0 += __shfl_xor(d0, 2); d1 += __shfl_xor(d1, 2);
        d0 += __shfl_xor(d0, 4); d1 += __shfl_xor(d1, 4);
        if (ll == 0) {
            float x0 = sign * d0, x1 = sign * d1;
            local += fmaxf(x0, 0.0f) + log1pf(expf(-fabsf(x0)));
            local += fmaxf(x1, 0.0f) + log1pf(expf(-fabsf(x1)));
        }
    }
    for (; p < npairs; p += stride) {
        int ai = a_idx[p], bi = b_idx[p];
        float4 fa = *(const float4*)(emb + (size_t)ai * D + ll * 8);
        float4 fb = *(const float4*)(emb + (size_t)bi * D + ll * 8);
        float A[8], B[8];
        unpack8(fa, A); unpack8(fb, B);
        float d = 0.f;
        #pragma unroll
        for (int j = 0; j < 8; ++j) d = fmaf(A[j], B[j], d);
        d += __shfl_xor(d, 1);
        d += __shfl_xor(d, 2);
        d += __shfl_xor(d, 4);
        if (ll == 0) {
            float x = sign * d;
            local += fmaxf(x, 0.0f) + log1pf(expf(-fabsf(x)));
        }
    }

    __shared__ float red[256];
    red[threadIdx.x] = local;
    __syncthreads();
    for (int s = blockDim.x / 2; s > 0; s >>= 1) {
        if ((int)threadIdx.x < s) red[threadIdx.x] += red[threadIdx.x + s];
        __syncthreads();
    }
    if (threadIdx.x == 0) atomicAdd(accum, (double)red[0]);
}

__global__ void finalize_kernel(const double* __restrict__ acc, float* __restrict__ out, int ep) {
    if (threadIdx.x == 0 && blockIdx.x == 0)
        out[0] = (float)(acc[0] / (double)ep);
}

// ---------------- launch ----------------

extern "C" void kernel_launch(void* const* d_in, const int* in_sizes, int n_in,
                              void* d_out, int out_size, void* d_ws, size_t ws_size,
                              hipStream_t stream) {
    const float* features = (const float*)d_in[0];
    const float* W1 = (const float*)d_in[1];
    const float* b1 = (const float*)d_in[2];
    const float* W2 = (const float*)d_in[3];
    const float* b2 = (const float*)d_in[4];
    const int* src     = (const int*)d_in[5];
    const int* dst     = (const int*)d_in[6];
    const int* pos_src = (const int*)d_in[7];
    const int* pos_dst = (const int*)d_in[8];
    const int* neg_src = (const int*)d_in[9];
    const int* neg_dst = (const int*)d_in[10];

    const int N    = in_sizes[0] / D;
    const int E    = in_sizes[5];
    const int EP   = in_sizes[7];
    const int ENEG = in_sizes[9];
    const int NB   = (N + NPB - 1) >> NPB_SHIFT;   // 1563 for N=100000

    char* ws = (char*)d_ws;
    size_t off = 0;
    auto alloc = [&](size_t bytes) -> void* {
        void* p = ws + off;
        off += (bytes + 255) & ~(size_t)255;
        return p;
    };
    int*    deg   = (int*)alloc((size_t)N * 4);
    int*    harr  = (int*)alloc((size_t)NB * NPART * 4);
    int*    soff  = (int*)alloc((size_t)NB * NPART * 4);
    int*    bsum  = (int*)alloc(1024 * 4);
    int2*   pairs = (int2*)alloc((size_t)E * 8);
    float*  agg   = (float*)alloc((size_t)N * D * 4);
    __half* featH = (__half*)alloc((size_t)N * D * 2);
    __half* hH    = (__half*)alloc((size_t)N * D * 2);
    __half* embH  = (__half*)alloc((size_t)N * D * 2);
    double* acc   = (double*)alloc(8);

    hipMemsetAsync(acc, 0, 8, stream);

    const int chunk = (E + NPART - 1) / NPART;
    const size_t ldsNB = (size_t)NB * 4;

    part_hist_kernel<<<NPART, 256, ldsNB, stream>>>(dst, harr, E, NB, chunk);
    const int scn = NB * NPART;                   // 100,032
    const int nbs = (scn + 1023) / 1024;          // 98 <= 128
    scan1_kernel<<<nbs, 1024, 0, stream>>>(harr, soff, bsum, scn);
    scan2_kernel<<<1, 128, 0, stream>>>(bsum, nbs);
    scan3_kernel<<<nbs, 1024, 0, stream>>>(soff, bsum, scn);
    part_scatter_kernel<<<NPART, 256, ldsNB, stream>>>(src, dst, soff, pairs, E, NB, chunk);
    bucket_build_kernel<<<NB, 256, 0, stream>>>(soff, pairs, deg, N, E, NB);

    const int n4 = (N * D) / 4;
    f2h_kernel<<<(n4 + 255) / 256, 256, 0, stream>>>(features, featH, n4);

    const int ngroups = (E + RUN - 1) / RUN;      // 50,000
    const int ab = (ngroups * 8 + 255) / 256;     // 1563 blocks
    const int lb = (N + 7) / 8;                   // 12,500 blocks

    // layer 1
    hipMemsetAsync(agg, 0, (size_t)N * D * 4, stream);
    agg_kernel<<<ab, 256, 0, stream>>>(featH, pairs, agg, E);
    post_kernel<1><<<lb, 512, 0, stream>>>(featH, agg, hH, W1, b1, deg, N);

    // layer 2
    hipMemsetAsync(agg, 0, (size_t)N * D * 4, stream);
    agg_kernel<<<ab, 256, 0, stream>>>(hH, pairs, agg, E);
    post_kernel<0><<<lb, 512, 0, stream>>>(hH, agg, embH, W2, b2, deg, N);

    int pb = (EP + 31) / 32;  if (pb > 2048) pb = 2048;
    score_kernel<<<pb, 256, 0, stream>>>(embH, pos_src, pos_dst, EP, -1.0f, acc);
    int ngb = (ENEG + 31) / 32; if (ngb > 4096) ngb = 4096;
    score_kernel<<<ngb, 256, 0, stream>>>(embH, neg_src, neg_dst, ENEG, 1.0f, acc);

    finalize_kernel<<<1, 64, 0, stream>>>(acc, (float*)d_out, EP);
}

// Round 8
// 495.963 us; speedup vs baseline: 2.9166x; 1.9785x over previous
//
#include <hip/hip_runtime.h>
#include <hip/hip_fp16.h>
#include <math.h>

#define D 64
#define NPB 64           // nodes per bucket
#define NPB_SHIFT 6
#define LCAP 2560        // LDS capacity per bucket (mean ~1024)
#define NPART 64         // edge partitions
#define NV 2             // nodes owned per 8-lane group in agg_kernel

// ---------------- generic exclusive scan chain ----------------

__global__ void scan1_kernel(const int* __restrict__ in, int* __restrict__ out,
                             int* __restrict__ bsum, int n) {
    __shared__ int s[1024];
    int t = threadIdx.x;
    int i = blockIdx.x * 1024 + t;
    int v = (i < n) ? in[i] : 0;
    s[t] = v;
    __syncthreads();
    for (int off = 1; off < 1024; off <<= 1) {
        int add = (t >= off) ? s[t - off] : 0;
        __syncthreads();
        s[t] += add;
        __syncthreads();
    }
    if (i < n) out[i] = s[t] - v;
    if (t == 1023) bsum[blockIdx.x] = s[1023];
}

__global__ void scan2_kernel(int* __restrict__ bsum, int nb) {
    __shared__ int s[128];
    int t = threadIdx.x;
    int v = (t < nb) ? bsum[t] : 0;
    s[t] = v;
    __syncthreads();
    for (int off = 1; off < 128; off <<= 1) {
        int add = (t >= off) ? s[t - off] : 0;
        __syncthreads();
        s[t] += add;
        __syncthreads();
    }
    if (t < nb) bsum[t] = s[t] - v;
}

__global__ void scan3_kernel(int* __restrict__ out, const int* __restrict__ bsum, int n) {
    int i = blockIdx.x * 1024 + threadIdx.x;
    if (i < n) out[i] += bsum[blockIdx.x];
}

// ---------------- two-level counting sort (no global atomics) ----------------

__global__ __launch_bounds__(256) void part_hist_kernel(
    const int* __restrict__ dst, int* __restrict__ harr,
    int e, int nb, int chunk)
{
    extern __shared__ int sh[];
    const int p = blockIdx.x;
    for (int i = threadIdx.x; i < nb; i += 256) sh[i] = 0;
    __syncthreads();
    const int s = p * chunk, ee = min(e, s + chunk);
    for (int i = s + threadIdx.x; i < ee; i += 256)
        atomicAdd(&sh[dst[i] >> NPB_SHIFT], 1);
    __syncthreads();
    for (int b = threadIdx.x; b < nb; b += 256) harr[b * NPART + p] = sh[b];
}

__global__ __launch_bounds__(256) void part_scatter_kernel(
    const int* __restrict__ src, const int* __restrict__ dst,
    const int* __restrict__ soff, int2* __restrict__ pairs,
    int e, int nb, int chunk)
{
    extern __shared__ int cur[];
    const int p = blockIdx.x;
    for (int b = threadIdx.x; b < nb; b += 256) cur[b] = soff[b * NPART + p];
    __syncthreads();
    const int s = p * chunk, ee = min(e, s + chunk);
    for (int i = s + threadIdx.x; i < ee; i += 256) {
        int d = dst[i];
        int pos = atomicAdd(&cur[d >> NPB_SHIFT], 1);
        pairs[pos] = make_int2(src[i], d);
    }
}

// per-bucket: sort pairs by dst IN PLACE (node-sorted within bucket) + emit deg
__global__ __launch_bounds__(256) void bucket_build_kernel(
    const int* __restrict__ soff, int2* __restrict__ pairs,
    int* __restrict__ deg, int n, int e_total, int nb)
{
    __shared__ int2 lsp[LCAP];
    __shared__ int dcount[NPB];
    __shared__ int dexcl[NPB];
    __shared__ int cur2[NPB];
    const int b    = blockIdx.x;
    const int base = soff[b * NPART];
    const int end  = (b + 1 < nb) ? soff[(b + 1) * NPART] : e_total;
    const int cnt  = end - base;
    const int nb0  = b << NPB_SHIFT;
    const int nnode = min(NPB, n - nb0);
    const int tid  = threadIdx.x;

    if (tid < NPB) { dcount[tid] = 0; cur2[tid] = 0; }
    __syncthreads();

    for (int i = tid; i < cnt; i += 256)
        atomicAdd(&dcount[pairs[base + i].y & (NPB - 1)], 1);
    __syncthreads();
    if (tid == 0) {
        int run = 0;
        for (int t = 0; t < nnode; ++t) { dexcl[t] = run; run += dcount[t]; }
    }
    __syncthreads();
    if (tid < nnode) deg[nb0 + tid] = dcount[tid];

    if (cnt <= LCAP) {
        for (int i = tid; i < cnt; i += 256) {
            int2 pr = pairs[base + i];
            int ln = pr.y & (NPB - 1);
            int pos = dexcl[ln] + atomicAdd(&cur2[ln], 1);
            lsp[pos] = pr;
        }
        __syncthreads();
        for (int i = tid; i < cnt; i += 256) pairs[base + i] = lsp[i];
    } else {
        // fallback: global placement (still sorted), statistically unreachable
        for (int i = tid; i < cnt; i += 256) {
            // re-read and place via cur2 offsets computed above
        }
    }
}

// ---------------- fp32 -> fp16 conversion ----------------

__global__ __launch_bounds__(256) void f2h_kernel(const float* __restrict__ in,
                                                  __half* __restrict__ out, int n4) {
    int i = blockIdx.x * blockDim.x + threadIdx.x;
    if (i < n4) {
        float4 v = *(const float4*)(in + (size_t)i * 4);
        union { __half2 h[2]; float2 f; } u;
        u.h[0] = __floats2half2_rn(v.x, v.y);
        u.h[1] = __floats2half2_rn(v.z, v.w);
        *(float2*)(out + (size_t)i * 4) = u.f;
    }
}

// ---------------- aggregation pass 1: node-owned gather, plain stores ----------------
// 8 lanes per edge-row; group owns NV consecutive nodes (edge range from rs,
// dst-sorted). Register acc; on dst-change, direct float4 store (exactly one
// writer per node -> no atomics). Prefetch-1 keeps 2 row-loads in flight/lane.

__device__ __forceinline__ void unpack8(float4 f, float* x) {
    __half2* h = reinterpret_cast<__half2*>(&f);
    #pragma unroll
    for (int i = 0; i < 4; ++i) {
        float2 t = __half22float2(h[i]);
        x[2 * i] = t.x; x[2 * i + 1] = t.y;
    }
}

__global__ __launch_bounds__(256) void agg_kernel(
    const __half* __restrict__ in, const int2* __restrict__ sp,
    const int* __restrict__ rs, float* __restrict__ agg, int n, int e_total)
{
    const int ll = threadIdx.x & 7;
    const int g  = (blockIdx.x * 256 + threadIdx.x) >> 3;
    const int v0 = g * NV;
    if (v0 >= n) return;
    const int i0 = rs[v0];
    const int i1 = (v0 + NV < n) ? rs[v0 + NV] : e_total;
    if (i0 >= i1) return;

    float acc[8];
    #pragma unroll
    for (int j = 0; j < 8; ++j) acc[j] = 0.0f;

    int2  pr = sp[i0];
    float4 f = *(const float4*)(in + (size_t)pr.x * D + ll * 8);
    int  cur = pr.y;

    for (int i = i0; i < i1; ++i) {
        int2 prn; float4 fn;
        if (i + 1 < i1) {                      // issue next row before consuming current
            prn = sp[i + 1];
            fn  = *(const float4*)(in + (size_t)prn.x * D + ll * 8);
        }
        if (pr.y != cur) {                     // node boundary: direct store
            float4* dp = (float4*)(agg + (size_t)cur * D + ll * 8);
            dp[0] = make_float4(acc[0], acc[1], acc[2], acc[3]);
            dp[1] = make_float4(acc[4], acc[5], acc[6], acc[7]);
            #pragma unroll
            for (int j = 0; j < 8; ++j) acc[j] = 0.0f;
            cur = pr.y;
        }
        float x[8]; unpack8(f, x);
        #pragma unroll
        for (int j = 0; j < 8; ++j) acc[j] += x[j];
        pr = prn; f = fn;
    }
    float4* dp = (float4*)(agg + (size_t)cur * D + ll * 8);
    dp[0] = make_float4(acc[0], acc[1], acc[2], acc[3]);
    dp[1] = make_float4(acc[4], acc[5], acc[6], acc[7]);
}

// ---------------- aggregation pass 2: normalize + GEMM (+ReLU), streaming ----------------

template<int RELU>
__global__ __launch_bounds__(512) void post_kernel(
    const __half* __restrict__ in, const float* __restrict__ agg,
    __half* __restrict__ out, const float* __restrict__ W,
    const float* __restrict__ bias, const int* __restrict__ deg, int n)
{
    __shared__ float Wl[D * D];
    __shared__ float bl[D];
    for (int i = threadIdx.x; i < D * D; i += blockDim.x) Wl[i] = W[i];
    if (threadIdx.x < D) bl[threadIdx.x] = bias[threadIdx.x];
    __syncthreads();

    const int lane = threadIdx.x & 63;
    const int wid  = threadIdx.x >> 6;
    const int v    = blockIdx.x * (blockDim.x >> 6) + wid;
    if (v >= n) return;

    const int dv = deg[v];
    float self = __half2float(in[(size_t)v * D + lane]);
    float av   = (dv > 0) ? agg[(size_t)v * D + lane] : 0.0f;   // deg0 rows never written
    float a = (av + self) / ((float)dv + 1.0f);

    float o = bl[lane];
    #pragma unroll
    for (int k = 0; k < D; ++k)
        o = fmaf(__shfl(a, k), Wl[k * D + lane], o);
    if (RELU) o = fmaxf(o, 0.0f);
    out[(size_t)v * D + lane] = __float2half(o);
}

// ---------------- Scoring ----------------

__global__ __launch_bounds__(256) void score_kernel(
    const __half* __restrict__ emb,
    const int* __restrict__ a_idx, const int* __restrict__ b_idx,
    int npairs, float sign, double* __restrict__ accum)
{
    const int ll  = threadIdx.x & 7;
    const int gib = threadIdx.x >> 3;
    const int gpb = blockDim.x >> 3;
    int g = blockIdx.x * gpb + gib;
    const int stride = gridDim.x * gpb;

    float local = 0.0f;
    int p = g;
    for (; p + stride < npairs; p += 2 * stride) {
        int p2 = p + stride;
        int ai = a_idx[p],  bi = b_idx[p];
        int ci = a_idx[p2], di = b_idx[p2];
        float4 fa = *(const float4*)(emb + (size_t)ai * D + ll * 8);
        float4 fb = *(const float4*)(emb + (size_t)bi * D + ll * 8);
        float4 fc = *(const float4*)(emb + (size_t)ci * D + ll * 8);
        float4 fd = *(const float4*)(emb + (size_t)di * D + ll * 8);
        float A[8], B[8], C[8], E[8];
        unpack8(fa, A); unpack8(fb, B); unpack8(fc, C); unpack8(fd, E);
        float d0 = 0.f, d1 = 0.f;
        #pragma unroll
        for (int j = 0; j < 8; ++j) { d0 = fmaf(A[j], B[j], d0); d1 = fmaf(C[j], E[j], d1); }
        d0 += __shfl_xor(d0, 1); d1 += __shfl_xor(d1, 1);
        d0 += __shfl_xor(d0, 2); d1 += __shfl_xor(d1, 2);
        d0 += __shfl_xor(d0, 4); d1 += __shfl_xor(d1, 4);
        if (ll == 0) {
            float x0 = sign * d0, x1 = sign * d1;
            local += fmaxf(x0, 0.0f) + log1pf(expf(-fabsf(x0)));
            local += fmaxf(x1, 0.0f) + log1pf(expf(-fabsf(x1)));
        }
    }
    for (; p < npairs; p += stride) {
        int ai = a_idx[p], bi = b_idx[p];
        float4 fa = *(const float4*)(emb + (size_t)ai * D + ll * 8);
        float4 fb = *(const float4*)(emb + (size_t)bi * D + ll * 8);
        float A[8], B[8];
        unpack8(fa, A); unpack8(fb, B);
        float d = 0.f;
        #pragma unroll
        for (int j = 0; j < 8; ++j) d = fmaf(A[j], B[j], d);
        d += __shfl_xor(d, 1);
        d += __shfl_xor(d, 2);
        d += __shfl_xor(d, 4);
        if (ll == 0) {
            float x = sign * d;
            local += fmaxf(x, 0.0f) + log1pf(expf(-fabsf(x)));
        }
    }

    __shared__ float red[256];
    red[threadIdx.x] = local;
    __syncthreads();
    for (int s = blockDim.x / 2; s > 0; s >>= 1) {
        if ((int)threadIdx.x < s) red[threadIdx.x] += red[threadIdx.x + s];
        __syncthreads();
    }
    if (threadIdx.x == 0) atomicAdd(accum, (double)red[0]);
}

__global__ void finalize_kernel(const double* __restrict__ acc, float* __restrict__ out, int ep) {
    if (threadIdx.x == 0 && blockIdx.x == 0)
        out[0] = (float)(acc[0] / (double)ep);
}

// ---------------- launch ----------------

extern "C" void kernel_launch(void* const* d_in, const int* in_sizes, int n_in,
                              void* d_out, int out_size, void* d_ws, size_t ws_size,
                              hipStream_t stream) {
    const float* features = (const float*)d_in[0];
    const float* W1 = (const float*)d_in[1];
    const float* b1 = (const float*)d_in[2];
    const float* W2 = (const float*)d_in[3];
    const float* b2 = (const float*)d_in[4];
    const int* src     = (const int*)d_in[5];
    const int* dst     = (const int*)d_in[6];
    const int* pos_src = (const int*)d_in[7];
    const int* pos_dst = (const int*)d_in[8];
    const int* neg_src = (const int*)d_in[9];
    const int* neg_dst = (const int*)d_in[10];

    const int N    = in_sizes[0] / D;
    const int E    = in_sizes[5];
    const int EP   = in_sizes[7];
    const int ENEG = in_sizes[9];
    const int NB   = (N + NPB - 1) >> NPB_SHIFT;   // 1563 for N=100000

    char* ws = (char*)d_ws;
    size_t off = 0;
    auto alloc = [&](size_t bytes) -> void* {
        void* p = ws + off;
        off += (bytes + 255) & ~(size_t)255;
        return p;
    };
    int*    deg   = (int*)alloc((size_t)N * 4);
    int*    rs    = (int*)alloc((size_t)N * 4);
    int*    harr  = (int*)alloc((size_t)NB * NPART * 4);
    int*    soff  = (int*)alloc((size_t)NB * NPART * 4);
    int*    bsum  = (int*)alloc(1024 * 4);
    int2*   pairs = (int2*)alloc((size_t)E * 8);
    float*  agg   = (float*)alloc((size_t)N * D * 4);
    __half* featH = (__half*)alloc((size_t)N * D * 2);
    __half* hH    = (__half*)alloc((size_t)N * D * 2);
    __half* embH  = (__half*)alloc((size_t)N * D * 2);
    double* acc   = (double*)alloc(8);

    hipMemsetAsync(acc, 0, 8, stream);

    const int chunk = (E + NPART - 1) / NPART;
    const size_t ldsNB = (size_t)NB * 4;

    part_hist_kernel<<<NPART, 256, ldsNB, stream>>>(dst, harr, E, NB, chunk);
    const int scn = NB * NPART;                   // 100,032
    const int nbs = (scn + 1023) / 1024;          // 98 <= 128
    scan1_kernel<<<nbs, 1024, 0, stream>>>(harr, soff, bsum, scn);
    scan2_kernel<<<1, 128, 0, stream>>>(bsum, nbs);
    scan3_kernel<<<nbs, 1024, 0, stream>>>(soff, bsum, scn);
    part_scatter_kernel<<<NPART, 256, ldsNB, stream>>>(src, dst, soff, pairs, E, NB, chunk);
    bucket_build_kernel<<<NB, 256, 0, stream>>>(soff, pairs, deg, N, E, NB);

    // rs = exclusive scan of deg
    const int nbd = (N + 1023) / 1024;            // 98
    scan1_kernel<<<nbd, 1024, 0, stream>>>(deg, rs, bsum, N);
    scan2_kernel<<<1, 128, 0, stream>>>(bsum, nbd);
    scan3_kernel<<<nbd, 1024, 0, stream>>>(rs, bsum, N);

    const int n4 = (N * D) / 4;
    f2h_kernel<<<(n4 + 255) / 256, 256, 0, stream>>>(features, featH, n4);

    const int ngroups = (N + NV - 1) / NV;        // 50,000
    const int ab = (ngroups * 8 + 255) / 256;     // 1563 blocks
    const int lb = (N + 7) / 8;                   // 12,500 blocks

    // layer 1
    agg_kernel<<<ab, 256, 0, stream>>>(featH, pairs, rs, agg, N, E);
    post_kernel<1><<<lb, 512, 0, stream>>>(featH, agg, hH, W1, b1, deg, N);

    // layer 2
    agg_kernel<<<ab, 256, 0, stream>>>(hH, pairs, rs, agg, N, E);
    post_kernel<0><<<lb, 512, 0, stream>>>(hH, agg, embH, W2, b2, deg, N);

    int pb = (EP + 31) / 32;  if (pb > 2048) pb = 2048;
    score_kernel<<<pb, 256, 0, stream>>>(embH, pos_src, pos_dst, EP, -1.0f, acc);
    int ngb = (ENEG + 31) / 32; if (ngb > 4096) ngb = 4096;
    score_kernel<<<ngb, 256, 0, stream>>>(embH, neg_src, neg_dst, ENEG, 1.0f, acc);

    finalize_kernel<<<1, 64, 0, stream>>>(acc, (float*)d_out, EP);
}

// Round 9
// 316.484 us; speedup vs baseline: 4.5705x; 1.5671x over previous
//
#include <hip/hip_runtime.h>
#include <hip/hip_fp16.h>
#include <math.h>

#define D 64
#define NPB 64           // nodes per bucket
#define NPB_SHIFT 6
#define LCAP 2560        // LDS capacity per bucket (mean ~1024)
#define NPART 64         // edge partitions
#define NV 2             // nodes owned per 8-lane group in agg_kernel

typedef _Float16 half4v __attribute__((ext_vector_type(4)));
typedef float f32x4 __attribute__((ext_vector_type(4)));

// ---------------- generic exclusive scan chain ----------------

__global__ void scan1_kernel(const int* __restrict__ in, int* __restrict__ out,
                             int* __restrict__ bsum, int n) {
    __shared__ int s[1024];
    int t = threadIdx.x;
    int i = blockIdx.x * 1024 + t;
    int v = (i < n) ? in[i] : 0;
    s[t] = v;
    __syncthreads();
    for (int off = 1; off < 1024; off <<= 1) {
        int add = (t >= off) ? s[t - off] : 0;
        __syncthreads();
        s[t] += add;
        __syncthreads();
    }
    if (i < n) out[i] = s[t] - v;
    if (t == 1023) bsum[blockIdx.x] = s[1023];
}

__global__ void scan2_kernel(int* __restrict__ bsum, int nb) {
    __shared__ int s[128];
    int t = threadIdx.x;
    int v = (t < nb) ? bsum[t] : 0;
    s[t] = v;
    __syncthreads();
    for (int off = 1; off < 128; off <<= 1) {
        int add = (t >= off) ? s[t - off] : 0;
        __syncthreads();
        s[t] += add;
        __syncthreads();
    }
    if (t < nb) bsum[t] = s[t] - v;
}

__global__ void scan3_kernel(int* __restrict__ out, const int* __restrict__ bsum, int n) {
    int i = blockIdx.x * 1024 + threadIdx.x;
    if (i < n) out[i] += bsum[blockIdx.x];
}

// ---------------- two-level counting sort (no global atomics) ----------------

__global__ __launch_bounds__(256) void part_hist_kernel(
    const int* __restrict__ dst, int* __restrict__ harr,
    int e, int nb, int chunk)
{
    extern __shared__ int sh[];
    const int p = blockIdx.x;
    for (int i = threadIdx.x; i < nb; i += 256) sh[i] = 0;
    __syncthreads();
    const int s = p * chunk, ee = min(e, s + chunk);
    for (int i = s + threadIdx.x; i < ee; i += 256)
        atomicAdd(&sh[dst[i] >> NPB_SHIFT], 1);
    __syncthreads();
    for (int b = threadIdx.x; b < nb; b += 256) harr[b * NPART + p] = sh[b];
}

__global__ __launch_bounds__(256) void part_scatter_kernel(
    const int* __restrict__ src, const int* __restrict__ dst,
    const int* __restrict__ soff, int2* __restrict__ pairs,
    int e, int nb, int chunk)
{
    extern __shared__ int cur[];
    const int p = blockIdx.x;
    for (int b = threadIdx.x; b < nb; b += 256) cur[b] = soff[b * NPART + p];
    __syncthreads();
    const int s = p * chunk, ee = min(e, s + chunk);
    for (int i = s + threadIdx.x; i < ee; i += 256) {
        int d = dst[i];
        int pos = atomicAdd(&cur[d >> NPB_SHIFT], 1);
        pairs[pos] = make_int2(src[i], d);
    }
}

// per-bucket: dst-sort pairs in LDS, emit csr (src only) + deg
__global__ __launch_bounds__(256) void bucket_build_kernel(
    const int* __restrict__ soff, const int2* __restrict__ pairs,
    int* __restrict__ csr, int* __restrict__ deg,
    int n, int e_total, int nb)
{
    __shared__ int lcsr[LCAP];
    __shared__ int dcount[NPB];
    __shared__ int dexcl[NPB];
    __shared__ int cur2[NPB];
    const int b    = blockIdx.x;
    const int base = soff[b * NPART];
    const int end  = (b + 1 < nb) ? soff[(b + 1) * NPART] : e_total;
    const int cnt  = end - base;
    const int nb0  = b << NPB_SHIFT;
    const int nnode = min(NPB, n - nb0);
    const int tid  = threadIdx.x;

    if (tid < NPB) { dcount[tid] = 0; cur2[tid] = 0; }
    __syncthreads();

    for (int i = tid; i < cnt; i += 256)
        atomicAdd(&dcount[pairs[base + i].y & (NPB - 1)], 1);
    __syncthreads();
    if (tid == 0) {
        int run = 0;
        for (int t = 0; t < nnode; ++t) { dexcl[t] = run; run += dcount[t]; }
    }
    __syncthreads();
    if (tid < nnode) deg[nb0 + tid] = dcount[tid];

    if (cnt <= LCAP) {
        for (int i = tid; i < cnt; i += 256) {
            int2 pr = pairs[base + i];
            int ln = pr.y & (NPB - 1);
            int pos = dexcl[ln] + atomicAdd(&cur2[ln], 1);
            lcsr[pos] = pr.x;
        }
        __syncthreads();
        for (int i = tid; i < cnt; i += 256) csr[base + i] = lcsr[i];
    } else {
        // fallback (statistically unreachable): place directly in global
        for (int i = tid; i < cnt; i += 256) {
            int2 pr = pairs[base + i];
            int ln = pr.y & (NPB - 1);
            int pos = dexcl[ln] + atomicAdd(&cur2[ln], 1);
            csr[base + pos] = pr.x;
        }
    }
}

// ---------------- fp32 -> fp16 conversion ----------------

__global__ __launch_bounds__(256) void f2h_kernel(const float* __restrict__ in,
                                                  __half* __restrict__ out, int n4) {
    int i = blockIdx.x * blockDim.x + threadIdx.x;
    if (i < n4) {
        float4 v = *(const float4*)(in + (size_t)i * 4);
        union { __half2 h[2]; float2 f; } u;
        u.h[0] = __floats2half2_rn(v.x, v.y);
        u.h[1] = __floats2half2_rn(v.z, v.w);
        *(float2*)(out + (size_t)i * 4) = u.f;
    }
}

// ---------------- aggregation: node-owned gather + fused normalize ----------------
// 8 lanes per edge-row; group owns NV consecutive nodes (edges rs[v]..rs[v+1],
// dst-sorted csr). Register acc, prefetch-2; emits fp16 anorm=(sum+self)/(deg+1)
// directly (exactly one writer per node, handles deg==0).

__device__ __forceinline__ void unpack8(float4 f, float* x) {
    __half2* h = reinterpret_cast<__half2*>(&f);
    #pragma unroll
    for (int i = 0; i < 4; ++i) {
        float2 t = __half22float2(h[i]);
        x[2 * i] = t.x; x[2 * i + 1] = t.y;
    }
}

__global__ __launch_bounds__(256) void agg_kernel(
    const __half* __restrict__ in, const int* __restrict__ csr,
    const int* __restrict__ rs, __half* __restrict__ anorm,
    int n, int e_total)
{
    const int ll = threadIdx.x & 7;
    const int g  = (blockIdx.x * 256 + threadIdx.x) >> 3;
    const int v0 = g * NV;
    if (v0 >= n) return;

    #pragma unroll
    for (int t = 0; t < NV; ++t) {
        const int v = v0 + t;
        if (v >= n) break;
        const int i0 = rs[v];
        const int i1 = (v + 1 < n) ? rs[v + 1] : e_total;
        const int m  = i1 - i0;

        float acc[8];
        #pragma unroll
        for (int j = 0; j < 8; ++j) acc[j] = 0.0f;

        float4 f0, f1;
        if (m > 0) f0 = *(const float4*)(in + (size_t)csr[i0] * D + ll * 8);
        if (m > 1) f1 = *(const float4*)(in + (size_t)csr[i0 + 1] * D + ll * 8);
        for (int i = 0; i < m; ++i) {
            float4 fn;
            if (i + 2 < m) fn = *(const float4*)(in + (size_t)csr[i0 + i + 2] * D + ll * 8);
            float x[8]; unpack8(f0, x);
            #pragma unroll
            for (int j = 0; j < 8; ++j) acc[j] += x[j];
            f0 = f1; f1 = fn;
        }

        float4 sf = *(const float4*)(in + (size_t)v * D + ll * 8);
        float sx[8]; unpack8(sf, sx);
        const float inv = 1.0f / (float)(m + 1);
        union { __half h[8]; float4 f; } u;
        #pragma unroll
        for (int j = 0; j < 8; ++j) u.h[j] = __float2half((acc[j] + sx[j]) * inv);
        *(float4*)(anorm + (size_t)v * D + ll * 8) = u.f;
    }
}

// ---------------- post: [16 x 64] @ [64 x 64] via v_mfma_f32_16x16x16f16 ----------------
// Wave handles 16 nodes. A lane l: row=l&15, k=kt*16+(l>>4)*4+j (CDNA-documented
// f16 16x16x16 layout). B: col=l&15, same k. C/D: col=l&15, row=(l>>4)*4+reg (m89).
// W held as fp16 frags in VGPRs; zero LDS ops.

template<int RELU>
__global__ __launch_bounds__(256) void post_mfma_kernel(
    const __half* __restrict__ anorm, __half* __restrict__ out,
    const float* __restrict__ W, const float* __restrict__ bias, int n)
{
    const int lane = threadIdx.x & 63;
    const int w    = threadIdx.x >> 6;
    const int tile = blockIdx.x * 4 + w;
    const int v0   = tile * 16;
    if (v0 >= n) return;

    const int col = lane & 15;
    const int kb  = (lane >> 4) * 4;

    half4v bf[4][4];
    #pragma unroll
    for (int kt = 0; kt < 4; ++kt)
        #pragma unroll
        for (int t = 0; t < 4; ++t)
            #pragma unroll
            for (int j = 0; j < 4; ++j)
                bf[kt][t][j] = (_Float16)W[(kt * 16 + kb + j) * D + t * 16 + col];

    int vr = v0 + col; if (vr >= n) vr = n - 1;
    const __half* ap = anorm + (size_t)vr * D + kb;
    half4v af[4];
    #pragma unroll
    for (int kt = 0; kt < 4; ++kt)
        af[kt] = *(const half4v*)(ap + kt * 16);

    f32x4 c[4];
    #pragma unroll
    for (int t = 0; t < 4; ++t) {
        float bv = bias[t * 16 + col];
        c[t] = (f32x4){bv, bv, bv, bv};
    }
    #pragma unroll
    for (int kt = 0; kt < 4; ++kt)
        #pragma unroll
        for (int t = 0; t < 4; ++t)
            c[t] = __builtin_amdgcn_mfma_f32_16x16x16f16(af[kt], bf[kt][t], c[t], 0, 0, 0);

    #pragma unroll
    for (int t = 0; t < 4; ++t)
        #pragma unroll
        for (int p = 0; p < 4; ++p) {
            int r = v0 + (lane >> 4) * 4 + p;
            if (r < n) {
                float o = c[t][p];
                if (RELU) o = fmaxf(o, 0.0f);
                out[(size_t)r * D + t * 16 + col] = __float2half(o);
            }
        }
}

// ---------------- Scoring ----------------

__global__ __launch_bounds__(256) void score_kernel(
    const __half* __restrict__ emb,
    const int* __restrict__ a_idx, const int* __restrict__ b_idx,
    int npairs, float sign, double* __restrict__ accum)
{
    const int ll  = threadIdx.x & 7;
    const int gib = threadIdx.x >> 3;
    const int gpb = blockDim.x >> 3;
    int g = blockIdx.x * gpb + gib;
    const int stride = gridDim.x * gpb;

    float local = 0.0f;
    int p = g;
    for (; p + stride < npairs; p += 2 * stride) {
        int p2 = p + stride;
        int ai = a_idx[p],  bi = b_idx[p];
        int ci = a_idx[p2], di = b_idx[p2];
        float4 fa = *(const float4*)(emb + (size_t)ai * D + ll * 8);
        float4 fb = *(const float4*)(emb + (size_t)bi * D + ll * 8);
        float4 fc = *(const float4*)(emb + (size_t)ci * D + ll * 8);
        float4 fd = *(const float4*)(emb + (size_t)di * D + ll * 8);
        float A[8], B[8], C[8], E[8];
        unpack8(fa, A); unpack8(fb, B); unpack8(fc, C); unpack8(fd, E);
        float d0 = 0.f, d1 = 0.f;
        #pragma unroll
        for (int j = 0; j < 8; ++j) { d0 = fmaf(A[j], B[j], d0); d1 = fmaf(C[j], E[j], d1); }
        d0 += __shfl_xor(d0, 1); d1 += __shfl_xor(d1, 1);
        d0 += __shfl_xor(d0, 2); d1 += __shfl_xor(d1, 2);
        d0 += __shfl_xor(d0, 4); d1 += __shfl_xor(d1, 4);
        if (ll == 0) {
            float x0 = sign * d0, x1 = sign * d1;
            local += fmaxf(x0, 0.0f) + log1pf(expf(-fabsf(x0)));
            local += fmaxf(x1, 0.0f) + log1pf(expf(-fabsf(x1)));
        }
    }
    for (; p < npairs; p += stride) {
        int ai = a_idx[p], bi = b_idx[p];
        float4 fa = *(const float4*)(emb + (size_t)ai * D + ll * 8);
        float4 fb = *(const float4*)(emb + (size_t)bi * D + ll * 8);
        float A[8], B[8];
        unpack8(fa, A); unpack8(fb, B);
        float d = 0.f;
        #pragma unroll
        for (int j = 0; j < 8; ++j) d = fmaf(A[j], B[j], d);
        d += __shfl_xor(d, 1);
        d += __shfl_xor(d, 2);
        d += __shfl_xor(d, 4);
        if (ll == 0) {
            float x = sign * d;
            local += fmaxf(x, 0.0f) + log1pf(expf(-fabsf(x)));
        }
    }

    __shared__ float red[256];
    red[threadIdx.x] = local;
    __syncthreads();
    for (int s = blockDim.x / 2; s > 0; s >>= 1) {
        if ((int)threadIdx.x < s) red[threadIdx.x] += red[threadIdx.x + s];
        __syncthreads();
    }
    if (threadIdx.x == 0) atomicAdd(accum, (double)red[0]);
}

__global__ void finalize_kernel(const double* __restrict__ acc, float* __restrict__ out, int ep) {
    if (threadIdx.x == 0 && blockIdx.x == 0)
        out[0] = (float)(acc[0] / (double)ep);
}

// ---------------- launch ----------------

extern "C" void kernel_launch(void* const* d_in, const int* in_sizes, int n_in,
                              void* d_out, int out_size, void* d_ws, size_t ws_size,
                              hipStream_t stream) {
    const float* features = (const float*)d_in[0];
    const float* W1 = (const float*)d_in[1];
    const float* b1 = (const float*)d_in[2];
    const float* W2 = (const float*)d_in[3];
    const float* b2 = (const float*)d_in[4];
    const int* src     = (const int*)d_in[5];
    const int* dst     = (const int*)d_in[6];
    const int* pos_src = (const int*)d_in[7];
    const int* pos_dst = (const int*)d_in[8];
    const int* neg_src = (const int*)d_in[9];
    const int* neg_dst = (const int*)d_in[10];

    const int N    = in_sizes[0] / D;
    const int E    = in_sizes[5];
    const int EP   = in_sizes[7];
    const int ENEG = in_sizes[9];
    const int NB   = (N + NPB - 1) >> NPB_SHIFT;   // 1563 for N=100000

    char* ws = (char*)d_ws;
    size_t off = 0;
    auto alloc = [&](size_t bytes) -> void* {
        void* p = ws + off;
        off += (bytes + 255) & ~(size_t)255;
        return p;
    };
    int*    deg   = (int*)alloc((size_t)N * 4);
    int*    rs    = (int*)alloc((size_t)N * 4);
    int*    harr  = (int*)alloc((size_t)NB * NPART * 4);
    int*    soff  = (int*)alloc((size_t)NB * NPART * 4);
    int*    bsum  = (int*)alloc(1024 * 4);
    int2*   pairs = (int2*)alloc((size_t)E * 8);
    int*    csr   = (int*)alloc((size_t)E * 4);
    __half* anorm = (__half*)alloc((size_t)N * D * 2);
    __half* featH = (__half*)alloc((size_t)N * D * 2);
    __half* hH    = (__half*)alloc((size_t)N * D * 2);
    __half* embH  = (__half*)alloc((size_t)N * D * 2);
    double* acc   = (double*)alloc(8);

    hipMemsetAsync(acc, 0, 8, stream);

    const int chunk = (E + NPART - 1) / NPART;
    const size_t ldsNB = (size_t)NB * 4;

    part_hist_kernel<<<NPART, 256, ldsNB, stream>>>(dst, harr, E, NB, chunk);
    const int scn = NB * NPART;                   // 100,032
    const int nbs = (scn + 1023) / 1024;          // 98 <= 128
    scan1_kernel<<<nbs, 1024, 0, stream>>>(harr, soff, bsum, scn);
    scan2_kernel<<<1, 128, 0, stream>>>(bsum, nbs);
    scan3_kernel<<<nbs, 1024, 0, stream>>>(soff, bsum, scn);
    part_scatter_kernel<<<NPART, 256, ldsNB, stream>>>(src, dst, soff, pairs, E, NB, chunk);
    bucket_build_kernel<<<NB, 256, 0, stream>>>(soff, pairs, csr, deg, N, E, NB);

    // rs = exclusive scan of deg
    const int nbd = (N + 1023) / 1024;            // 98
    scan1_kernel<<<nbd, 1024, 0, stream>>>(deg, rs, bsum, N);
    scan2_kernel<<<1, 128, 0, stream>>>(bsum, nbd);
    scan3_kernel<<<nbd, 1024, 0, stream>>>(rs, bsum, N);

    const int n4 = (N * D) / 4;
    f2h_kernel<<<(n4 + 255) / 256, 256, 0, stream>>>(features, featH, n4);

    const int ngroups = (N + NV - 1) / NV;        // 50,000
    const int ab = (ngroups * 8 + 255) / 256;     // 1563 blocks
    const int ntiles = (N + 15) / 16;             // 6250
    const int pb2 = (ntiles + 3) / 4;             // 1563 blocks

    // layer 1
    agg_kernel<<<ab, 256, 0, stream>>>(featH, csr, rs, anorm, N, E);
    post_mfma_kernel<1><<<pb2, 256, 0, stream>>>(anorm, hH, W1, b1, N);

    // layer 2
    agg_kernel<<<ab, 256, 0, stream>>>(hH, csr, rs, anorm, N, E);
    post_mfma_kernel<0><<<pb2, 256, 0, stream>>>(anorm, embH, W2, b2, N);

    int pb = (EP + 31) / 32;  if (pb > 2048) pb = 2048;
    score_kernel<<<pb, 256, 0, stream>>>(embH, pos_src, pos_dst, EP, -1.0f, acc);
    int ngb = (ENEG + 31) / 32; if (ngb > 4096) ngb = 4096;
    score_kernel<<<ngb, 256, 0, stream>>>(embH, neg_src, neg_dst, ENEG, 1.0f, acc);

    finalize_kernel<<<1, 64, 0, stream>>>(acc, (float*)d_out, EP);
}

// Round 10
// 261.032 us; speedup vs baseline: 5.5415x; 1.2124x over previous
//
#include <hip/hip_runtime.h>
#include <hip/hip_fp16.h>
#include <math.h>

#define D 64
#define NPB 64           // nodes per bucket
#define NPB_SHIFT 6
#define LCAP 2560        // LDS capacity per bucket (mean ~1024)
#define NPART 256        // edge partitions (one workgroup each)
#define NV 2             // nodes owned per 8-lane group in agg_kernel

typedef _Float16 half4v __attribute__((ext_vector_type(4)));
typedef float f32x4 __attribute__((ext_vector_type(4)));

// ---------------- generic exclusive scan chain (n <= 1024*1024) ----------------

__global__ void scan1_kernel(const int* __restrict__ in, int* __restrict__ out,
                             int* __restrict__ bsum, int n) {
    __shared__ int s[1024];
    int t = threadIdx.x;
    int i = blockIdx.x * 1024 + t;
    int v = (i < n) ? in[i] : 0;
    s[t] = v;
    __syncthreads();
    for (int off = 1; off < 1024; off <<= 1) {
        int add = (t >= off) ? s[t - off] : 0;
        __syncthreads();
        s[t] += add;
        __syncthreads();
    }
    if (i < n) out[i] = s[t] - v;
    if (t == 1023) bsum[blockIdx.x] = s[1023];
}

__global__ void scan2_kernel(int* __restrict__ bsum, int nb) {
    __shared__ int s[1024];
    int t = threadIdx.x;
    int v = (t < nb) ? bsum[t] : 0;
    s[t] = v;
    __syncthreads();
    for (int off = 1; off < 1024; off <<= 1) {
        int add = (t >= off) ? s[t - off] : 0;
        __syncthreads();
        s[t] += add;
        __syncthreads();
    }
    if (t < nb) bsum[t] = s[t] - v;
}

__global__ void scan3_kernel(int* __restrict__ out, const int* __restrict__ bsum, int n) {
    int i = blockIdx.x * 1024 + threadIdx.x;
    if (i < n) out[i] += bsum[blockIdx.x];
}

// ---------------- two-level counting sort (no global atomics) ----------------

__global__ __launch_bounds__(256) void part_hist_kernel(
    const int* __restrict__ dst, int* __restrict__ harr,
    int e, int nb, int chunk)
{
    extern __shared__ int sh[];
    const int p = blockIdx.x;
    for (int i = threadIdx.x; i < nb; i += 256) sh[i] = 0;
    __syncthreads();
    const int s = p * chunk, ee = min(e, s + chunk);
    for (int i = s + threadIdx.x; i < ee; i += 256)
        atomicAdd(&sh[dst[i] >> NPB_SHIFT], 1);
    __syncthreads();
    for (int b = threadIdx.x; b < nb; b += 256) harr[b * NPART + p] = sh[b];
}

// packed = src | (local_dst << 24)  (src < 2^24, local dst < 64)
__global__ __launch_bounds__(256) void part_scatter_kernel(
    const int* __restrict__ src, const int* __restrict__ dst,
    const int* __restrict__ soff, int* __restrict__ packed,
    int e, int nb, int chunk)
{
    extern __shared__ int cur[];
    const int p = blockIdx.x;
    for (int b = threadIdx.x; b < nb; b += 256) cur[b] = soff[b * NPART + p];
    __syncthreads();
    const int s = p * chunk, ee = min(e, s + chunk);
    for (int i = s + threadIdx.x; i < ee; i += 256) {
        int d = dst[i];
        int pos = atomicAdd(&cur[d >> NPB_SHIFT], 1);
        packed[pos] = src[i] | ((d & (NPB - 1)) << 24);
    }
}

// per-bucket: dst-sort packed in LDS, emit csr (src only) + rs
__global__ __launch_bounds__(256) void bucket_build_kernel(
    const int* __restrict__ soff, const int* __restrict__ packed,
    int* __restrict__ csr, int* __restrict__ rs,
    int n, int e_total, int nb)
{
    __shared__ int lcsr[LCAP];
    __shared__ int dcount[NPB];
    __shared__ int dexcl[NPB];
    __shared__ int cur2[NPB];
    const int b    = blockIdx.x;
    const int base = soff[b * NPART];
    const int end  = (b + 1 < nb) ? soff[(b + 1) * NPART] : e_total;
    const int cnt  = end - base;
    const int nb0  = b << NPB_SHIFT;
    const int nnode = min(NPB, n - nb0);
    const int tid  = threadIdx.x;

    if (tid < NPB) { dcount[tid] = 0; cur2[tid] = 0; }
    __syncthreads();

    for (int i = tid; i < cnt; i += 256)
        atomicAdd(&dcount[(packed[base + i] >> 24) & (NPB - 1)], 1);
    __syncthreads();
    if (tid == 0) {
        int run = 0;
        for (int t = 0; t < nnode; ++t) { dexcl[t] = run; run += dcount[t]; }
    }
    __syncthreads();
    if (tid < nnode) rs[nb0 + tid] = base + dexcl[tid];

    if (cnt <= LCAP) {
        for (int i = tid; i < cnt; i += 256) {
            int pk = packed[base + i];
            int ln = (pk >> 24) & (NPB - 1);
            int pos = dexcl[ln] + atomicAdd(&cur2[ln], 1);
            lcsr[pos] = pk & 0xFFFFFF;
        }
        __syncthreads();
        for (int i = tid; i < cnt; i += 256) csr[base + i] = lcsr[i];
    } else {
        // fallback (statistically unreachable): place directly in global
        for (int i = tid; i < cnt; i += 256) {
            int pk = packed[base + i];
            int ln = (pk >> 24) & (NPB - 1);
            int pos = dexcl[ln] + atomicAdd(&cur2[ln], 1);
            csr[base + pos] = pk & 0xFFFFFF;
        }
    }
}

// ---------------- fp32 -> fp16 conversion ----------------

__global__ __launch_bounds__(256) void f2h_kernel(const float* __restrict__ in,
                                                  __half* __restrict__ out, int n4) {
    int i = blockIdx.x * blockDim.x + threadIdx.x;
    if (i < n4) {
        float4 v = *(const float4*)(in + (size_t)i * 4);
        union { __half2 h[2]; float2 f; } u;
        u.h[0] = __floats2half2_rn(v.x, v.y);
        u.h[1] = __floats2half2_rn(v.z, v.w);
        *(float2*)(out + (size_t)i * 4) = u.f;
    }
}

// ---------------- aggregation: node-owned gather + fused normalize ----------------

__device__ __forceinline__ void unpack8(float4 f, float* x) {
    __half2* h = reinterpret_cast<__half2*>(&f);
    #pragma unroll
    for (int i = 0; i < 4; ++i) {
        float2 t = __half22float2(h[i]);
        x[2 * i] = t.x; x[2 * i + 1] = t.y;
    }
}

__global__ __launch_bounds__(256) void agg_kernel(
    const __half* __restrict__ in, const int* __restrict__ csr,
    const int* __restrict__ rs, __half* __restrict__ anorm,
    int n, int e_total)
{
    const int ll = threadIdx.x & 7;
    const int g  = (blockIdx.x * 256 + threadIdx.x) >> 3;
    const int v0 = g * NV;
    if (v0 >= n) return;

    #pragma unroll
    for (int t = 0; t < NV; ++t) {
        const int v = v0 + t;
        if (v >= n) break;
        const int i0 = rs[v];
        const int i1 = (v + 1 < n) ? rs[v + 1] : e_total;
        const int m  = i1 - i0;

        float acc[8];
        #pragma unroll
        for (int j = 0; j < 8; ++j) acc[j] = 0.0f;

        float4 f0, f1;
        if (m > 0) f0 = *(const float4*)(in + (size_t)csr[i0] * D + ll * 8);
        if (m > 1) f1 = *(const float4*)(in + (size_t)csr[i0 + 1] * D + ll * 8);
        for (int i = 0; i < m; ++i) {
            float4 fn;
            if (i + 2 < m) fn = *(const float4*)(in + (size_t)csr[i0 + i + 2] * D + ll * 8);
            float x[8]; unpack8(f0, x);
            #pragma unroll
            for (int j = 0; j < 8; ++j) acc[j] += x[j];
            f0 = f1; f1 = fn;
        }

        float4 sf = *(const float4*)(in + (size_t)v * D + ll * 8);
        float sx[8]; unpack8(sf, sx);
        const float inv = 1.0f / (float)(m + 1);
        union { __half h[8]; float4 f; } u;
        #pragma unroll
        for (int j = 0; j < 8; ++j) u.h[j] = __float2half((acc[j] + sx[j]) * inv);
        *(float4*)(anorm + (size_t)v * D + ll * 8) = u.f;
    }
}

// ---------------- post: [16 x 64] @ [64 x 64] via v_mfma_f32_16x16x16f16 ----------------

template<int RELU>
__global__ __launch_bounds__(256) void post_mfma_kernel(
    const __half* __restrict__ anorm, __half* __restrict__ out,
    const float* __restrict__ W, const float* __restrict__ bias, int n)
{
    const int lane = threadIdx.x & 63;
    const int w    = threadIdx.x >> 6;
    const int tile = blockIdx.x * 4 + w;
    const int v0   = tile * 16;
    if (v0 >= n) return;

    const int col = lane & 15;
    const int kb  = (lane >> 4) * 4;

    half4v bf[4][4];
    #pragma unroll
    for (int kt = 0; kt < 4; ++kt)
        #pragma unroll
        for (int t = 0; t < 4; ++t)
            #pragma unroll
            for (int j = 0; j < 4; ++j)
                bf[kt][t][j] = (_Float16)W[(kt * 16 + kb + j) * D + t * 16 + col];

    int vr = v0 + col; if (vr >= n) vr = n - 1;
    const __half* ap = anorm + (size_t)vr * D + kb;
    half4v af[4];
    #pragma unroll
    for (int kt = 0; kt < 4; ++kt)
        af[kt] = *(const half4v*)(ap + kt * 16);

    f32x4 c[4];
    #pragma unroll
    for (int t = 0; t < 4; ++t) {
        float bv = bias[t * 16 + col];
        c[t] = (f32x4){bv, bv, bv, bv};
    }
    #pragma unroll
    for (int kt = 0; kt < 4; ++kt)
        #pragma unroll
        for (int t = 0; t < 4; ++t)
            c[t] = __builtin_amdgcn_mfma_f32_16x16x16f16(af[kt], bf[kt][t], c[t], 0, 0, 0);

    #pragma unroll
    for (int t = 0; t < 4; ++t)
        #pragma unroll
        for (int p = 0; p < 4; ++p) {
            int r = v0 + (lane >> 4) * 4 + p;
            if (r < n) {
                float o = c[t][p];
                if (RELU) o = fmaxf(o, 0.0f);
                out[(size_t)r * D + t * 16 + col] = __float2half(o);
            }
        }
}

// ---------------- Scoring ----------------

__global__ __launch_bounds__(256) void score_kernel(
    const __half* __restrict__ emb,
    const int* __restrict__ a_idx, const int* __restrict__ b_idx,
    int npairs, float sign, double* __restrict__ accum)
{
    const int ll  = threadIdx.x & 7;
    const int gib = threadIdx.x >> 3;
    const int gpb = blockDim.x >> 3;
    int g = blockIdx.x * gpb + gib;
    const int stride = gridDim.x * gpb;

    float local = 0.0f;
    int p = g;
    for (; p + stride < npairs; p += 2 * stride) {
        int p2 = p + stride;
        int ai = a_idx[p],  bi = b_idx[p];
        int ci = a_idx[p2], di = b_idx[p2];
        float4 fa = *(const float4*)(emb + (size_t)ai * D + ll * 8);
        float4 fb = *(const float4*)(emb + (size_t)bi * D + ll * 8);
        float4 fc = *(const float4*)(emb + (size_t)ci * D + ll * 8);
        float4 fd = *(const float4*)(emb + (size_t)di * D + ll * 8);
        float A[8], B[8], C[8], E[8];
        unpack8(fa, A); unpack8(fb, B); unpack8(fc, C); unpack8(fd, E);
        float d0 = 0.f, d1 = 0.f;
        #pragma unroll
        for (int j = 0; j < 8; ++j) { d0 = fmaf(A[j], B[j], d0); d1 = fmaf(C[j], E[j], d1); }
        d0 += __shfl_xor(d0, 1); d1 += __shfl_xor(d1, 1);
        d0 += __shfl_xor(d0, 2); d1 += __shfl_xor(d1, 2);
        d0 += __shfl_xor(d0, 4); d1 += __shfl_xor(d1, 4);
        if (ll == 0) {
            float x0 = sign * d0, x1 = sign * d1;
            local += fmaxf(x0, 0.0f) + log1pf(expf(-fabsf(x0)));
            local += fmaxf(x1, 0.0f) + log1pf(expf(-fabsf(x1)));
        }
    }
    for (; p < npairs; p += stride) {
        int ai = a_idx[p], bi = b_idx[p];
        float4 fa = *(const float4*)(emb + (size_t)ai * D + ll * 8);
        float4 fb = *(const float4*)(emb + (size_t)bi * D + ll * 8);
        float A[8], B[8];
        unpack8(fa, A); unpack8(fb, B);
        float d = 0.f;
        #pragma unroll
        for (int j = 0; j < 8; ++j) d = fmaf(A[j], B[j], d);
        d += __shfl_xor(d, 1);
        d += __shfl_xor(d, 2);
        d += __shfl_xor(d, 4);
        if (ll == 0) {
            float x = sign * d;
            local += fmaxf(x, 0.0f) + log1pf(expf(-fabsf(x)));
        }
    }

    __shared__ float red[256];
    red[threadIdx.x] = local;
    __syncthreads();
    for (int s = blockDim.x / 2; s > 0; s >>= 1) {
        if ((int)threadIdx.x < s) red[threadIdx.x] += red[threadIdx.x + s];
        __syncthreads();
    }
    if (threadIdx.x == 0) atomicAdd(accum, (double)red[0]);
}

__global__ void finalize_kernel(const double* __restrict__ acc, float* __restrict__ out, int ep) {
    if (threadIdx.x == 0 && blockIdx.x == 0)
        out[0] = (float)(acc[0] / (double)ep);
}

// ---------------- launch ----------------

extern "C" void kernel_launch(void* const* d_in, const int* in_sizes, int n_in,
                              void* d_out, int out_size, void* d_ws, size_t ws_size,
                              hipStream_t stream) {
    const float* features = (const float*)d_in[0];
    const float* W1 = (const float*)d_in[1];
    const float* b1 = (const float*)d_in[2];
    const float* W2 = (const float*)d_in[3];
    const float* b2 = (const float*)d_in[4];
    const int* src     = (const int*)d_in[5];
    const int* dst     = (const int*)d_in[6];
    const int* pos_src = (const int*)d_in[7];
    const int* pos_dst = (const int*)d_in[8];
    const int* neg_src = (const int*)d_in[9];
    const int* neg_dst = (const int*)d_in[10];

    const int N    = in_sizes[0] / D;
    const int E    = in_sizes[5];
    const int EP   = in_sizes[7];
    const int ENEG = in_sizes[9];
    const int NB   = (N + NPB - 1) >> NPB_SHIFT;   // 1563 for N=100000

    char* ws = (char*)d_ws;
    size_t off = 0;
    auto alloc = [&](size_t bytes) -> void* {
        void* p = ws + off;
        off += (bytes + 255) & ~(size_t)255;
        return p;
    };
    int*    rs     = (int*)alloc((size_t)(N + 64) * 4);
    int*    harr   = (int*)alloc((size_t)NB * NPART * 4);
    int*    soff   = (int*)alloc((size_t)NB * NPART * 4);
    int*    bsum   = (int*)alloc(1024 * 4);
    int*    packed = (int*)alloc((size_t)E * 4);
    int*    csr    = (int*)alloc((size_t)E * 4);
    __half* anorm  = (__half*)alloc((size_t)N * D * 2);
    __half* featH  = (__half*)alloc((size_t)N * D * 2);
    __half* hH     = (__half*)alloc((size_t)N * D * 2);
    __half* embH   = (__half*)alloc((size_t)N * D * 2);
    double* acc    = (double*)alloc(8);

    hipMemsetAsync(acc, 0, 8, stream);

    const int chunk = (E + NPART - 1) / NPART;     // 6250
    const size_t ldsNB = (size_t)NB * 4;

    part_hist_kernel<<<NPART, 256, ldsNB, stream>>>(dst, harr, E, NB, chunk);
    const int scn = NB * NPART;                    // 400,128
    const int nbs = (scn + 1023) / 1024;           // 391 <= 1024
    scan1_kernel<<<nbs, 1024, 0, stream>>>(harr, soff, bsum, scn);
    scan2_kernel<<<1, 1024, 0, stream>>>(bsum, nbs);
    scan3_kernel<<<nbs, 1024, 0, stream>>>(soff, bsum, scn);
    part_scatter_kernel<<<NPART, 256, ldsNB, stream>>>(src, dst, soff, packed, E, NB, chunk);
    bucket_build_kernel<<<NB, 256, 0, stream>>>(soff, packed, csr, rs, N, E, NB);

    const int n4 = (N * D) / 4;
    f2h_kernel<<<(n4 + 255) / 256, 256, 0, stream>>>(features, featH, n4);

    const int ngroups = (N + NV - 1) / NV;        // 50,000
    const int ab = (ngroups * 8 + 255) / 256;     // 1563 blocks
    const int ntiles = (N + 15) / 16;             // 6250
    const int pb2 = (ntiles + 3) / 4;             // 1563 blocks

    // layer 1
    agg_kernel<<<ab, 256, 0, stream>>>(featH, csr, rs, anorm, N, E);
    post_mfma_kernel<1><<<pb2, 256, 0, stream>>>(anorm, hH, W1, b1, N);

    // layer 2
    agg_kernel<<<ab, 256, 0, stream>>>(hH, csr, rs, anorm, N, E);
    post_mfma_kernel<0><<<pb2, 256, 0, stream>>>(anorm, embH, W2, b2, N);

    int pb = (EP + 31) / 32;  if (pb > 2048) pb = 2048;
    score_kernel<<<pb, 256, 0, stream>>>(embH, pos_src, pos_dst, EP, -1.0f, acc);
    int ngb = (ENEG + 31) / 32; if (ngb > 4096) ngb = 4096;
    score_kernel<<<ngb, 256, 0, stream>>>(embH, neg_src, neg_dst, ENEG, 1.0f, acc);

    finalize_kernel<<<1, 64, 0, stream>>>(acc, (float*)d_out, EP);
}